// Round 9
// baseline (1352.281 us; speedup 1.0000x reference)
//
#include <hip/hip_runtime.h>
#include <hip/hip_bf16.h>
#include <math.h>

// B=32, T=128, D_IN=32, H1=1024, H=2048, PEN=1024, C=64, P=4
// Inputs/outputs are FLOAT32 (per the reference dtypes; labels int32).
// Internally: f32 -> bf16 conversion at GEMM staging, bf16 MFMA compute,
// bf16 activations, f32 final outputs. Loose threshold (1.02e-2) admits bf16.

typedef __bf16 bf16_t;
typedef __bf16 bf16x4 __attribute__((ext_vector_type(4)));
typedef __bf16 bf16x8 __attribute__((ext_vector_type(8)));
typedef float  f32x4  __attribute__((ext_vector_type(4)));
typedef int    i32x4  __attribute__((ext_vector_type(4)));
typedef unsigned int u32;
typedef unsigned long long u64;

static __device__ __forceinline__ void zero4(f32x4& v) {
  v[0] = 0.0f; v[1] = 0.0f; v[2] = 0.0f; v[3] = 0.0f;
}

template <typename T>
static __device__ __forceinline__ bf16x8 load8_as_bf16(const T* p);
template <>
__device__ __forceinline__ bf16x8 load8_as_bf16<bf16_t>(const bf16_t* p) {
  return *(const bf16x8*)p;
}
template <>
__device__ __forceinline__ bf16x8 load8_as_bf16<float>(const float* p) {
  bf16x8 v;
#pragma unroll
  for (int u = 0; u < 8; ++u) v[u] = (bf16_t)p[u];
  return v;
}

// async global->LDS 16B copy: LDS dest is wave-uniform base + lane*16 (HW),
// global src is per-lane.
static __device__ __forceinline__ void gload16(const bf16_t* g, bf16_t* l) {
  __builtin_amdgcn_global_load_lds(
      (const __attribute__((address_space(1))) u32*)g,
      (__attribute__((address_space(3))) u32*)l, 16, 0, 0);
}

// ---------------------------------------------------------------------------
// f32 -> bf16 bulk convert (8 elems/thread). n8 = n/8.
// ---------------------------------------------------------------------------
__global__ __launch_bounds__(256) void cvt_f32_bf16(
    const float* __restrict__ s, bf16_t* __restrict__ d, int n8)
{
  const int i = blockIdx.x * 256 + threadIdx.x;
  if (i < n8) {
    const float* p = s + (size_t)i * 8;
    bf16x8 v;
#pragma unroll
    for (int u = 0; u < 8; ++u) v[u] = (bf16_t)p[u];
    *(bf16x8*)(d + (size_t)i * 8) = v;
  }
}

// ---------------------------------------------------------------------------
// GEMM (f32 path, layer1): C = act(A*B^T + bias), 128x128 tile, BK=32.
// tmajor: store C row m = b*128+t at physical row t*32+b.
// ---------------------------------------------------------------------------
template <typename TA, typename TB>
__global__ __launch_bounds__(256) void gemm_bt(
    const TA* __restrict__ A, const TB* __restrict__ Bm,
    const float* __restrict__ bias, bf16_t* __restrict__ C,
    int M, int N, int K, int relu, int tmajor)
{
  __shared__ __align__(16) bf16_t As[128 * 32];
  __shared__ __align__(16) bf16_t Bs[128 * 32];

  const int tid  = threadIdx.x;
  const int lane = tid & 63;
  const int wave = tid >> 6;
  const int q    = lane >> 4;
  const int l15  = lane & 15;
  const int wr   = wave >> 1;
  const int wc   = wave & 1;
  const int m0   = blockIdx.y * 128;
  const int n0   = blockIdx.x * 128;

  f32x4 acc[4][4];
#pragma unroll
  for (int i = 0; i < 4; ++i)
#pragma unroll
    for (int j = 0; j < 4; ++j) zero4(acc[i][j]);

  const int se = wave * 512 + lane * 8;

  const int kt_count = K >> 5;
  for (int kt = 0; kt < kt_count; ++kt) {
    const int k0 = kt << 5;

    bf16x8 av[2], bv[2];
#pragma unroll
    for (int c = 0; c < 2; ++c) {
      const int e   = c * 2048 + se;
      const int row = e >> 5;
      const int col = e & 31;
      av[c] = load8_as_bf16<TA>(&A [(size_t)(m0 + row) * K + k0 + col]);
      bv[c] = load8_as_bf16<TB>(&Bm[(size_t)(n0 + row) * K + k0 + col]);
    }

    __syncthreads();
#pragma unroll
    for (int c = 0; c < 2; ++c) {
      *(bf16x8*)&As[c * 2048 + se] = av[c];
      *(bf16x8*)&Bs[c * 2048 + se] = bv[c];
    }
    __syncthreads();

    bf16x8 af[4], bfv[4];
#pragma unroll
    for (int i = 0; i < 4; ++i)
      af[i] = *(const bf16x8*)&As[(wr * 64 + i * 16 + l15) * 32 + q * 8];
#pragma unroll
    for (int j = 0; j < 4; ++j)
      bfv[j] = *(const bf16x8*)&Bs[(wc * 64 + j * 16 + l15) * 32 + q * 8];

#pragma unroll
    for (int i = 0; i < 4; ++i)
#pragma unroll
      for (int j = 0; j < 4; ++j)
        acc[i][j] = __builtin_amdgcn_mfma_f32_16x16x32_bf16(af[i], bfv[j], acc[i][j], 0, 0, 0);
  }

#pragma unroll
  for (int j = 0; j < 4; ++j) {
    const int n = n0 + wc * 64 + j * 16 + l15;
    const float bvl = bias[n];
#pragma unroll
    for (int i = 0; i < 4; ++i) {
      const int mbase = m0 + wr * 64 + i * 16 + q * 4;
#pragma unroll
      for (int r = 0; r < 4; ++r) {
        float v = acc[i][j][r] + bvl;
        if (relu) v = v > 0.0f ? v : 0.0f;
        const int m = mbase + r;
        const int pm = tmajor ? ((m & 127) * 32 + (m >> 7)) : m;
        C[(size_t)pm * N + n] = (bf16_t)v;
      }
    }
  }
}

// ---------------------------------------------------------------------------
// GEMM (bf16 x bf16) with global_load_lds staging (m97 pattern). Used for
// layer2 (rows already t-major-consistent: row-wise op, any row order).
// ---------------------------------------------------------------------------
__global__ __launch_bounds__(256) void gemm_lds(
    const bf16_t* __restrict__ A, const bf16_t* __restrict__ Bm,
    const float* __restrict__ bias, bf16_t* __restrict__ C,
    int M, int N, int K, int relu)
{
  __shared__ __align__(16) bf16_t As[128 * 32];
  __shared__ __align__(16) bf16_t Bs[128 * 32];

  const int tid  = threadIdx.x;
  const int lane = tid & 63;
  const int wave = tid >> 6;
  const int q    = lane >> 4;
  const int l15  = lane & 15;
  const int wr   = wave >> 1;
  const int wc   = wave & 1;
  const int m0   = blockIdx.y * 128;
  const int n0   = blockIdx.x * 128;

  f32x4 acc[4][4];
#pragma unroll
  for (int i = 0; i < 4; ++i)
#pragma unroll
    for (int j = 0; j < 4; ++j) zero4(acc[i][j]);

  const int sew = wave * 512;
  const int se  = sew + lane * 8;

  const int kt_count = K >> 5;
  for (int kt = 0; kt < kt_count; ++kt) {
    const int k0 = kt << 5;

    __syncthreads();
#pragma unroll
    for (int c = 0; c < 2; ++c) {
      const int e   = c * 2048 + se;
      const int row = e >> 5;
      const int col = e & 31;
      gload16(&A [(size_t)(m0 + row) * K + k0 + col], &As[c * 2048 + sew]);
      gload16(&Bm[(size_t)(n0 + row) * K + k0 + col], &Bs[c * 2048 + sew]);
    }
    asm volatile("s_waitcnt vmcnt(0)" ::: "memory");
    __syncthreads();

    bf16x8 af[4], bfv[4];
#pragma unroll
    for (int i = 0; i < 4; ++i)
      af[i] = *(const bf16x8*)&As[(wr * 64 + i * 16 + l15) * 32 + q * 8];
#pragma unroll
    for (int j = 0; j < 4; ++j)
      bfv[j] = *(const bf16x8*)&Bs[(wc * 64 + j * 16 + l15) * 32 + q * 8];

#pragma unroll
    for (int i = 0; i < 4; ++i)
#pragma unroll
      for (int j = 0; j < 4; ++j)
        acc[i][j] = __builtin_amdgcn_mfma_f32_16x16x32_bf16(af[i], bfv[j], acc[i][j], 0, 0, 0);
  }

#pragma unroll
  for (int j = 0; j < 4; ++j) {
    const int n = n0 + wc * 64 + j * 16 + l15;
    const float bvl = bias[n];
#pragma unroll
    for (int i = 0; i < 4; ++i) {
      const int mbase = m0 + wr * 64 + i * 16 + q * 4;
#pragma unroll
      for (int r = 0; r < 4; ++r) {
        float v = acc[i][j][r] + bvl;
        if (relu) v = v > 0.0f ? v : 0.0f;
        C[(size_t)(mbase + r) * N + n] = (bf16_t)v;
      }
    }
  }
}

// ---------------------------------------------------------------------------
// Round 9 = round 8 (scan + fused layer3 + fused xp GEMM) with the
// WORKSPACE BUG FIXED: round 8 mapped out_s (8 MB) into a 2 MB slot, so
// out_s rows >=1024 overwrote the arrival flags / tile counters and the
// flag stores stomped ~512K out_s elements (absmax 2.4e-2). out_s now
// overlays out1t (dead after layer2); arr/tcnt live in dedicated space.
// All kernel logic is unchanged from round 8.
// ---------------------------------------------------------------------------
#define WROW 2056   // 2048 + 8 bf16 pad
#define NCOPY 8

// ---- produce helpers (xp tile GEMM, 8 waves, tile 128x128, BK=32) ----
static __device__ __forceinline__ void produce_issue(
    int c, int buf, int wg, int tid, int wave,
    const bf16_t* out2t, const bf16_t* W_ihb, char* scr)
{
  const int tile_i = c >> 6;
  const int id = wg + (tile_i << 8);
  const int k0 = (c & 63) << 5;
  bf16_t* dstA = (bf16_t*)(scr + buf * 16384);
  bf16_t* dstB = dstA + 4096;
  if (tid < 256) {
    const int tc = id / 48;
    const bf16_t* sb = out2t + (size_t)tc * 128 * 2048 + k0;
    const int g0 = tid;
    gload16(sb + (size_t)(g0 >> 2) * 2048 + (g0 & 3) * 8, dstA + (wave << 9));
    const int g1 = tid + 256;
    gload16(sb + (size_t)(g1 >> 2) * 2048 + (g1 & 3) * 8,
            dstA + 2048 + (wave << 9));
  } else {
    const int nc = id % 48;
    const int w4 = wave - 4;
    const bf16_t* sb = W_ihb + (size_t)nc * 128 * 2048 + k0;
    const int g0 = tid - 256;
    gload16(sb + (size_t)(g0 >> 2) * 2048 + (g0 & 3) * 8, dstB + (w4 << 9));
    const int g1 = g0 + 256;
    gload16(sb + (size_t)(g1 >> 2) * 2048 + (g1 & 3) * 8,
            dstB + 2048 + (w4 << 9));
  }
}

static __device__ __forceinline__ void produce_mfma(
    int buf, int wave, int q, int l15, char* scr, f32x4 (&pacc)[4][2])
{
  const bf16_t* pA = (const bf16_t*)(scr + buf * 16384);
  const bf16_t* pB = pA + 4096;
  const int wr = wave >> 2, wc = wave & 3;
  bf16x8 af[4], bfv[2];
#pragma unroll
  for (int i = 0; i < 4; ++i)
    af[i] = *(const bf16x8*)&pA[(wr * 64 + i * 16 + l15) * 32 + q * 8];
#pragma unroll
  for (int j = 0; j < 2; ++j)
    bfv[j] = *(const bf16x8*)&pB[(wc * 32 + j * 16 + l15) * 32 + q * 8];
#pragma unroll
  for (int i = 0; i < 4; ++i)
#pragma unroll
    for (int j = 0; j < 2; ++j)
      pacc[i][j] = __builtin_amdgcn_mfma_f32_16x16x32_bf16(af[i], bfv[j], pacc[i][j], 0, 0, 0);
}

static __device__ __forceinline__ void produce_epilogue(
    int c, int wg, int tid, int wave, int q, int l15,
    const float* b_ih, bf16_t* xpring, unsigned* tcnt, char* scr,
    f32x4 (&pacc)[4][2])
{
  const int tile_i = c >> 6;
  const int id = wg + (tile_i << 8);
  const int tc = id / 48, nc = id % 48;
  const int wr = wave >> 2, wc = wave & 3;
  bf16_t* tld = (bf16_t*)scr;    // [64][128], no staging in flight here
  float bv[2];
#pragma unroll
  for (int j = 0; j < 2; ++j) bv[j] = b_ih[nc * 128 + wc * 32 + j * 16 + l15];
#pragma unroll
  for (int half = 0; half < 2; ++half) {
    __syncthreads();
    if (wr == half) {
#pragma unroll
      for (int i = 0; i < 4; ++i)
#pragma unroll
        for (int j = 0; j < 2; ++j)
#pragma unroll
          for (int r = 0; r < 4; ++r)
            tld[(i * 16 + q * 4 + r) * 128 + wc * 32 + j * 16 + l15] =
                (bf16_t)(pacc[i][j][r] + bv[j]);
    }
    __syncthreads();
    const int slotbase = (tc & 15) * 128 + half * 64;
#pragma unroll
    for (int s = 0; s < 2; ++s) {
      const int g = tid * 2 + s;
      const int row = g >> 4, col = (g & 15) << 3;
      const i32x4 val = *(const i32x4*)&tld[row * 128 + col];
      bf16_t* dst = xpring + (size_t)(slotbase + row) * 6144 + nc * 128 + col;
      asm volatile("global_store_dwordx4 %0, %1, off sc0 sc1"
                   :: "v"(dst), "v"(val) : "memory");
    }
  }
  asm volatile("s_waitcnt vmcnt(0)" ::: "memory");   // tile at LLC
  __syncthreads();
  if (tid == 0)
    __hip_atomic_fetch_add(tcnt + tc, 1u, __ATOMIC_RELAXED,
                           __HIP_MEMORY_SCOPE_AGENT);
#pragma unroll
  for (int i = 0; i < 4; ++i) { zero4(pacc[i][0]); zero4(pacc[i][1]); }
}

static __device__ __forceinline__ void produce_run(
    int c0, int n, int wg, int tid, int wave, int q, int l15,
    const bf16_t* out2t, const bf16_t* W_ihb, const float* b_ih,
    bf16_t* xpring, unsigned* tcnt, char* scr, f32x4 (&pacc)[4][2])
{
  asm volatile("s_waitcnt vmcnt(0)" ::: "memory");   // exact-count baseline
  produce_issue(c0, 0, wg, tid, wave, out2t, W_ihb, scr);
  for (int s = 0; s < n; ++s) {
    const int c = c0 + s;
    if (s + 1 < n) {
      produce_issue(c + 1, (s + 1) & 1, wg, tid, wave, out2t, W_ihb, scr);
      asm volatile("s_waitcnt vmcnt(2)" ::: "memory");  // chunk c landed
    } else {
      asm volatile("s_waitcnt vmcnt(0)" ::: "memory");
    }
    __syncthreads();
    produce_mfma(s & 1, wave, q, l15, scr, pacc);
    __syncthreads();
    if ((c & 63) == 63)   // runs never cross tiles -> this is s == n-1
      produce_epilogue(c, wg, tid, wave, q, l15, b_ih, xpring, tcnt, scr, pacc);
  }
}

__global__ __launch_bounds__(512, 1) void gru_persistent(
    const float* __restrict__ W_hh, const float* __restrict__ b_hh,
    bf16_t* __restrict__ hs, unsigned* __restrict__ arr,
    const float* __restrict__ W3, const float* __restrict__ b3,
    bf16_t* __restrict__ out_s,
    const bf16_t* __restrict__ out2t, const bf16_t* __restrict__ W_ihb,
    const float* __restrict__ b_ih, bf16_t* __restrict__ xpring,
    unsigned* __restrict__ tcnt)
{
  __shared__ __align__(16) bf16_t Ws[24 * WROW];            // 98,688 B
  __shared__ __align__(16) bf16_t W3s[4 * WROW];            // 16,448 B
  // scratch union (38,912 B):
  //   scan phase: hp_p[8][32][28] @0 | hp3[8][32][8] @28672 |
  //               stg[32][8] @36864 | xps[32][3][8] @37376
  //   produce:    staging dbuf 2x16KB @0 (hp_p dead there)
  //   epilogue:   tld[64][128] @0 (no staging in flight)
  __shared__ __align__(16) char scr[38912];

  auto hp_p = (float (*)[32][28])(scr);
  auto hp3  = (float (*)[32][8])(scr + 28672);
  auto stg  = (unsigned short (*)[8])(scr + 36864);
  auto xps  = (__bf16 (*)[3][8])(scr + 37376);

  const int tid  = threadIdx.x;
  const int lane = tid & 63;
  const int wave = tid >> 6;
  const int q    = lane >> 4;
  const int l15  = lane & 15;
  const int bid  = blockIdx.x;
  const int wg   = bid;
  const int j0   = bid * 8;       // h columns owned
  const int j0s  = bid * 4;       // out_s columns owned
  const int k0w  = wave * 256;

  // ---- Stage W_hh slice into LDS once (f32 -> bf16) ----
  for (int m = 0; m < 24; ++m) {
    const int gate = m >> 3;
    const float* src = W_hh + (size_t)(gate * 2048 + j0 + (m & 7)) * 2048;
    const int c = tid * 4;
    bf16x4 v;
#pragma unroll
    for (int u = 0; u < 4; ++u) v[u] = (bf16_t)src[c + u];
    *(bf16x4*)&Ws[m * WROW + c] = v;
  }
  // ---- Stage W3 slice into LDS once (f32 -> bf16) ----
  for (int m = 0; m < 4; ++m) {
    const float* src = W3 + (size_t)(j0s + m) * 2048;
    const int c = tid * 4;
    bf16x4 v;
#pragma unroll
    for (int u = 0; u < 4; ++u) v[u] = (bf16_t)src[c + u];
    *(bf16x4*)&W3s[m * WROW + c] = v;
  }

  // pointwise mapping: waves 0-3 (tid<256) -> (batch b, local col jj)
  const bool pw = tid < 256;
  const int b  = (tid >> 3) & 31;
  const int jj = tid & 7;
  const int jg = j0 + jj;
  float bh_r = 0.f, bh_z = 0.f, bh_n = 0.f;
  if (pw) {
    bh_r = b_hh[jg];
    bh_z = b_hh[2048 + jg];
    bh_n = b_hh[4096 + jg];
  }
  // out_s reduce mapping: waves 4-5 (tid in [256,384)) -> (batch, col)
  const bool sw = (tid >= 256) && (tid < 384);
  const int b3t = (tid - 256) >> 2;
  const int c3  = (tid - 256) & 3;
  float b3v = 0.f;
  if (sw) b3v = b3[j0s + c3];

  // xp loader mapping: tid<192 -> (bb, gate xg, half xh)
  const int bb = tid / 6;
  const int xg = (tid % 6) >> 1;
  const int xh = tid & 1;

  // matmul A-tiles: tile0 row = l15 (gates r,z), tile1 row = 16+(l15&7)
  const bf16_t* arow0 = &Ws[(size_t)l15 * WROW + k0w];
  const bf16_t* arow1 = &Ws[(size_t)(16 + (l15 & 7)) * WROW + k0w];
  const bf16_t* arow3 = &W3s[(size_t)(l15 & 3) * WROW + k0w];

  f32x4 pacc[4][2];
#pragma unroll
  for (int i = 0; i < 4; ++i) { zero4(pacc[i][0]); zero4(pacc[i][1]); }

  float hcur = 0.0f;              // this thread's own h(b, jg)

  __syncthreads();   // Ws/W3s staged

  // ---- pre-phase: produce own tile 0 (covers tc = wg/48 in 0..5) ----
  produce_run(0, 64, wg, tid, wave, q, l15, out2t, W_ihb, b_ih,
              xpring, tcnt, scr, pacc);

  for (int t = 0; t < 128; ++t) {
    // ---- step-produce: chunks 64+4t .. +3 (t<80), in tile-bounded runs ----
    if (t < 80) {
      int c = 64 + 4 * t, left = 4;
      while (left > 0) {
        int n = 64 - (c & 63); if (n > left) n = left;
        produce_run(c, n, wg, tid, wave, q, l15, out2t, W_ihb, b_ih,
                    xpring, tcnt, scr, pacc);
        c += n; left -= n;
      }
    }

    // ---- poll: own h-producer flags (t>0) AND xp counter[t>>2] ----
    {
      const int tcn = t >> 2;
      const u64 tgt = 0x0000000100000001ull;
      const u64* f64p = (const u64*)(arr +
          ((size_t)(t > 0 ? t - 1 : 0) * NCOPY + (bid & 7)) * 256) + wave * 16;
      int guard = 0;
      for (;;) {
        u64 v = tgt; unsigned cc = 48;
        if (t > 0 && lane < 16)
          v = __hip_atomic_load(f64p + lane, __ATOMIC_RELAXED,
                                __HIP_MEMORY_SCOPE_AGENT);
        if (lane == 16)
          cc = __hip_atomic_load(tcnt + tcn, __ATOMIC_RELAXED,
                                 __HIP_MEMORY_SCOPE_AGENT);
        if (__all(v == tgt && cc >= 48)) break;
        __builtin_amdgcn_s_sleep(1);
        if (++guard > (1 << 20)) break;   // safety: never hang
      }
    }

    // ---- xp gate loads: L2-bypassing (ring reuses addresses) ----
    u64 xv = 0;
    if (tid < 192) {
      const int slot = (t >> 2) & 15;
      const size_t srow = (size_t)(slot * 128 + (t & 3) * 32 + bb);
      const u64* src = (const u64*)(xpring + srow * 6144 + xg * 2048 + j0) + xh;
      xv = __hip_atomic_load(src, __ATOMIC_RELAXED, __HIP_MEMORY_SCOPE_AGENT);
    }

    if (t > 0) {
      // ---- hprev fragment burst: 16 independent 16B loads ----
      bf16x8 bfr[2][8];
#pragma unroll
      for (int ct = 0; ct < 2; ++ct) {
        const bf16_t* bp_ = hs + ((size_t)(ct * 16 + l15) * 128 + (t - 1)) * 2048
                               + k0w + q * 8;
#pragma unroll
        for (int win = 0; win < 8; ++win)
          bfr[ct][win] = *(const bf16x8*)(bp_ + win * 32);
      }

      f32x4 acc[2][2];
#pragma unroll
      for (int rt = 0; rt < 2; ++rt)
#pragma unroll
        for (int ct = 0; ct < 2; ++ct) zero4(acc[rt][ct]);

#pragma unroll
      for (int win = 0; win < 8; ++win) {
        const bf16x8 a0 = *(const bf16x8*)(arow0 + win * 32 + q * 8);
        const bf16x8 a1 = *(const bf16x8*)(arow1 + win * 32 + q * 8);
        acc[0][0] = __builtin_amdgcn_mfma_f32_16x16x32_bf16(a0, bfr[0][win], acc[0][0], 0, 0, 0);
        acc[0][1] = __builtin_amdgcn_mfma_f32_16x16x32_bf16(a0, bfr[1][win], acc[0][1], 0, 0, 0);
        acc[1][0] = __builtin_amdgcn_mfma_f32_16x16x32_bf16(a1, bfr[0][win], acc[1][0], 0, 0, 0);
        acc[1][1] = __builtin_amdgcn_mfma_f32_16x16x32_bf16(a1, bfr[1][win], acc[1][1], 0, 0, 0);
      }

      // fused layer3: out_s partials for t-1, reusing bfr
      f32x4 acc3[2];
      zero4(acc3[0]); zero4(acc3[1]);
#pragma unroll
      for (int win = 0; win < 8; ++win) {
        const bf16x8 a3 = *(const bf16x8*)(arow3 + win * 32 + q * 8);
        acc3[0] = __builtin_amdgcn_mfma_f32_16x16x32_bf16(a3, bfr[0][win], acc3[0], 0, 0, 0);
        acc3[1] = __builtin_amdgcn_mfma_f32_16x16x32_bf16(a3, bfr[1][win], acc3[1], 0, 0, 0);
      }

      // partials: D col = l15 (batch within ct-tile), row = q*4+reg
#pragma unroll
      for (int ct = 0; ct < 2; ++ct) {
        *(f32x4*)&hp_p[wave][ct * 16 + l15][q * 4] = acc[0][ct];
        if (q < 2)
          *(f32x4*)&hp_p[wave][ct * 16 + l15][16 + q * 4] = acc[1][ct];
      }
      if (q == 0) {
        *(f32x4*)&hp3[wave][l15][0]      = acc3[0];
        *(f32x4*)&hp3[wave][16 + l15][0] = acc3[1];
      }
    }
    // deposit xp gates to LDS (load latency hidden under burst/MFMA)
    if (tid < 192)
      ((u64*)&xps[bb][xg][0])[xh] = xv;
    __syncthreads();   // (B) partials + xps ready

    if (pw) {
      float pr = 0.0f, pz = 0.0f, pn = 0.0f;
      if (t > 0) {
#pragma unroll
        for (int w = 0; w < 8; ++w) {
          pr += hp_p[w][b][jj];
          pz += hp_p[w][b][8 + jj];
          pn += hp_p[w][b][16 + jj];
        }
      }
      const float xr = (float)xps[b][0][jj];
      const float xz = (float)xps[b][1][jj];
      const float xn = (float)xps[b][2][jj];
      const float r_ = 1.0f / (1.0f + __expf(-(xr + pr + bh_r)));
      const float z_ = 1.0f / (1.0f + __expf(-(xz + pz + bh_z)));
      const float aa = xn + r_ * (pn + bh_n);
      const float et = __expf(-2.0f * aa);
      const float n_ = (1.0f - et) / (1.0f + et);
      hcur = (1.0f - z_) * n_ + z_ * hcur;

      union { bf16_t h; unsigned short u; } cv; cv.h = (bf16_t)hcur;
      stg[b][jj] = cv.u;
    } else if (sw && t > 0) {
      // fused layer3 reduce + relu + store out_s[:, t-1]
      float s3 = 0.0f;
#pragma unroll
      for (int w = 0; w < 8; ++w) s3 += hp3[w][b3t][c3];
      s3 += b3v;
      if (s3 < 0.0f) s3 = 0.0f;
      out_s[((size_t)b3t * 128 + (t - 1)) * 1024 + j0s + c3] = (bf16_t)s3;
    }
    __syncthreads();   // (A) stage ready; all LDS reads of step t done

    // ---- packed h store: wave 0 only, 32 x 16B coalesced sc0sc1 ----
    if (wave == 0 && lane < 32) {
      const i32x4 val = *(const i32x4*)&stg[lane][0];
      bf16_t* dst = hs + ((size_t)lane * 128 + t) * 2048 + j0;
      asm volatile("global_store_dwordx4 %0, %1, off sc0 sc1"
                   :: "v"(dst), "v"(val) : "memory");
    }
    if (wave == 0) {
      asm volatile("s_waitcnt vmcnt(0)" ::: "memory");  // stores at LLC
      if (lane < NCOPY)
        __hip_atomic_store(arr + ((size_t)t * NCOPY + lane) * 256 + bid, 1u,
                           __ATOMIC_RELAXED, __HIP_MEMORY_SCOPE_AGENT);
    }
    // waves 1-7 free-run into the next step's produce/poll here
  }

  // ---- epilogue: out_s[:, 127] (needs h[127], flags published above) ----
  {
    const int c = bid & 7;
    const u64* f64p =
        (const u64*)(arr + ((size_t)127 * NCOPY + c) * 256) + wave * 16;
    const u64 tgt = 0x0000000100000001ull;
    int guard = 0;
    for (;;) {
      u64 v = tgt;
      if (lane < 16)
        v = __hip_atomic_load(f64p + lane, __ATOMIC_RELAXED,
                              __HIP_MEMORY_SCOPE_AGENT);
      if (__all(v == tgt)) break;
      __builtin_amdgcn_s_sleep(1);
      if (++guard > (1 << 20)) break;
    }

    f32x4 acc3[2];
    zero4(acc3[0]); zero4(acc3[1]);
#pragma unroll
    for (int ct = 0; ct < 2; ++ct) {
      const bf16_t* bp_ = hs + ((size_t)(ct * 16 + l15) * 128 + 127) * 2048
                             + k0w + q * 8;
#pragma unroll
      for (int win = 0; win < 8; ++win) {
        const bf16x8 bv = *(const bf16x8*)(bp_ + win * 32);
        const bf16x8 a3 = *(const bf16x8*)(arow3 + win * 32 + q * 8);
        acc3[ct] = __builtin_amdgcn_mfma_f32_16x16x32_bf16(a3, bv, acc3[ct], 0, 0, 0);
      }
    }
    __syncthreads();
    if (q == 0) {
      *(f32x4*)&hp3[wave][l15][0]      = acc3[0];
      *(f32x4*)&hp3[wave][16 + l15][0] = acc3[1];
    }
    __syncthreads();
    if (sw) {
      float s3 = 0.0f;
#pragma unroll
      for (int w = 0; w < 8; ++w) s3 += hp3[w][b3t][c3];
      s3 += b3v;
      if (s3 < 0.0f) s3 = 0.0f;
      out_s[((size_t)b3t * 128 + 127) * 1024 + j0s + c3] = (bf16_t)s3;
    }
  }
}

// ---------------------------------------------------------------------------
// Heads: per (b,t): 3 scalar heads + 4 sigmoid heads, 1024-dot each with a
// label-gathered f32 weight row. out_s is bf16, OUTPUT IS FLOAT32.
// ---------------------------------------------------------------------------
__global__ __launch_bounds__(256) void heads_kernel(
    const bf16_t* __restrict__ out_s, const int* __restrict__ labels,
    const float* __restrict__ W4, const float* __restrict__ b4,
    const float* __restrict__ W5, const float* __restrict__ b5,
    const float* __restrict__ W6, const float* __restrict__ b6,
    const float* __restrict__ Wp, const float* __restrict__ bp,
    float* __restrict__ out)
{
  const int bt  = blockIdx.x;
  const int b   = bt >> 7;         // T = 128
  const int lab = labels[b];
  const bf16_t* os  = out_s + (size_t)bt * 1024;
  const float* w4  = W4 + (size_t)lab * 1024;
  const float* w5  = W5 + (size_t)lab * 1024;
  const float* w6  = W6 + (size_t)lab * 1024;
  const float* wp0 = Wp + (size_t)lab * 1024;   // + p*65536 for plane p

  float s[7] = {0, 0, 0, 0, 0, 0, 0};
  for (int d = threadIdx.x; d < 1024; d += 256) {
    const float v = (float)os[d];
    s[0] += v * w4[d];
    s[1] += v * w5[d];
    s[2] += v * w6[d];
    s[3] += v * wp0[d];
    s[4] += v * wp0[65536 + d];
    s[5] += v * wp0[131072 + d];
    s[6] += v * wp0[196608 + d];
  }
#pragma unroll
  for (int i = 0; i < 7; ++i)
    for (int off = 32; off > 0; off >>= 1)
      s[i] += __shfl_down(s[i], off, 64);

  __shared__ float red[4][7];
  const int lane = threadIdx.x & 63, wave = threadIdx.x >> 6;
  if (lane == 0)
    for (int i = 0; i < 7; ++i) red[wave][i] = s[i];
  __syncthreads();
  if (threadIdx.x == 0) {
    float tsum[7];
    for (int i = 0; i < 7; ++i)
      tsum[i] = red[0][i] + red[1][i] + red[2][i] + red[3][i];
    out[bt]        = tsum[0] + b4[lab];
    out[4096 + bt] = tsum[1] + b5[lab];
    out[8192 + bt] = tsum[2] + b6[lab];
#pragma unroll
    for (int p = 0; p < 4; ++p) {
      const float v = tsum[3 + p] + bp[p * 64 + lab];
      out[12288 + p * 4096 + bt] = 1.0f / (1.0f + __expf(-v));
    }
  }
}

// ---------------------------------------------------------------------------
extern "C" void kernel_launch(void* const* d_in, const int* in_sizes, int n_in,
                              void* d_out, int out_size, void* d_ws, size_t ws_size,
                              hipStream_t stream)
{
  const float* x     = (const float*)d_in[0];
  const int*   label = (const int*)d_in[1];
  const float* W1    = (const float*)d_in[2];
  const float* b1    = (const float*)d_in[3];
  const float* W2    = (const float*)d_in[4];
  const float* b2    = (const float*)d_in[5];
  const float* W_ih  = (const float*)d_in[6];
  const float* b_ih  = (const float*)d_in[7];
  const float* W_hh  = (const float*)d_in[8];
  const float* b_hh  = (const float*)d_in[9];
  const float* W3    = (const float*)d_in[10];
  const float* b3    = (const float*)d_in[11];
  const float* W4    = (const float*)d_in[12];
  const float* b4    = (const float*)d_in[13];
  const float* W5    = (const float*)d_in[14];
  const float* b5    = (const float*)d_in[15];
  const float* W6    = (const float*)d_in[16];
  const float* b6    = (const float*)d_in[17];
  const float* Wp    = (const float*)d_in[18];
  const float* bp    = (const float*)d_in[19];

  // Workspace map (96 MB), bf16 internals — FIXED vs round 8:
  //   W_ihb  [0,24)   bf16 W_ih          (cvt -> gru produce end)
  //   out2t  [24,40)  4096x2048 t-major  (layer2 -> gru produce end)
  //   xpring [40,64)  16 x 128 x 6144    (gru internal)
  //   hs     [64,80)  (B,T,2048)         (gru internal)
  //   arr    [80,81)  h arrival flags    (memset 0)
  //   tcnt   [81,+128B) 32 xp tile counters (memset 0)
  //   out1t  [84,92)  4096x1024 t-major  (layer1 -> layer2, then dead)
  //   out_s  [84,92)  4096x1024 (8 MB!)  (gru -> heads; overlays out1t)
  //   W2b    [92,96)  bf16 W2            (cvt -> layer2)
  char* ws = (char*)d_ws;
  bf16_t* W_ihb  = (bf16_t*)(ws);
  bf16_t* out2t  = (bf16_t*)(ws + (24u << 20));
  bf16_t* xpring = (bf16_t*)(ws + (40u << 20));
  bf16_t* hs     = (bf16_t*)(ws + (64u << 20));
  unsigned* arr  = (unsigned*)(ws + (80u << 20));
  unsigned* tcnt = (unsigned*)(ws + (81u << 20));
  bf16_t* out1t  = (bf16_t*)(ws + (84u << 20));
  bf16_t* out_s  = (bf16_t*)(ws + (84u << 20));   // overlays out1t (dead)
  bf16_t* W2b    = (bf16_t*)(ws + (92u << 20));
  float*  outp   = (float*)d_out;

  hipMemsetAsync(d_out, 0, (size_t)out_size * sizeof(float), stream);
  hipMemsetAsync(ws + (80u << 20), 0, (1u << 20) + 4096, stream);  // arr+tcnt

  dim3 blk(256);
  // pre-convert f32 weights -> bf16
  cvt_f32_bf16<<<dim3(6144), blk, 0, stream>>>(W_ih, W_ihb, 1572864);
  cvt_f32_bf16<<<dim3(1024), blk, 0, stream>>>(W2, W2b, 262144);
  // layer1: (4096x32)*(1024x32)^T, relu, t-major out
  gemm_bt<float, float><<<dim3(8, 32), blk, 0, stream>>>(x, W1, b1, out1t, 4096, 1024, 32, 1, 1);
  // layer2: (4096x1024)*(2048x1024)^T, relu (rows t-major-consistent)
  gemm_lds<<<dim3(16, 32), blk, 0, stream>>>(out1t, W2b, b2, out2t, 4096, 2048, 1024, 1);
  // GRU scan + fused layer3 + fused xp GEMM: persistent cooperative kernel
  {
    void* gru_args[] = { (void*)&W_hh, (void*)&b_hh, (void*)&hs, (void*)&arr,
                         (void*)&W3, (void*)&b3, (void*)&out_s,
                         (void*)&out2t, (void*)&W_ihb, (void*)&b_ih,
                         (void*)&xpring, (void*)&tcnt };
    hipLaunchCooperativeKernel((void*)gru_persistent, dim3(256), dim3(512),
                               gru_args, 0, stream);
  }
  // heads (f32 weights, f32 out)
  heads_kernel<<<dim3(4096), blk, 0, stream>>>(out_s, label, W4, b4, W5, b5, W6, b6, Wp, bp, outp);
}

// Round 10
// 1291.513 us; speedup vs baseline: 1.0471x; 1.0471x over previous
//
#include <hip/hip_runtime.h>
#include <hip/hip_bf16.h>
#include <math.h>

// B=32, T=128, D_IN=32, H1=1024, H=2048, PEN=1024, C=64, P=4
// Inputs/outputs are FLOAT32 (per the reference dtypes; labels int32).
// Internally: f32 -> bf16 conversion at GEMM staging, bf16 MFMA compute,
// bf16 activations, f32 final outputs. Loose threshold (1.02e-2) admits bf16.

typedef __bf16 bf16_t;
typedef __bf16 bf16x4 __attribute__((ext_vector_type(4)));
typedef __bf16 bf16x8 __attribute__((ext_vector_type(8)));
typedef float  f32x4  __attribute__((ext_vector_type(4)));
typedef int    i32x4  __attribute__((ext_vector_type(4)));
typedef unsigned int u32;
typedef unsigned long long u64;

static __device__ __forceinline__ void zero4(f32x4& v) {
  v[0] = 0.0f; v[1] = 0.0f; v[2] = 0.0f; v[3] = 0.0f;
}

template <typename T>
static __device__ __forceinline__ bf16x8 load8_as_bf16(const T* p);
template <>
__device__ __forceinline__ bf16x8 load8_as_bf16<bf16_t>(const bf16_t* p) {
  return *(const bf16x8*)p;
}
template <>
__device__ __forceinline__ bf16x8 load8_as_bf16<float>(const float* p) {
  bf16x8 v;
#pragma unroll
  for (int u = 0; u < 8; ++u) v[u] = (bf16_t)p[u];
  return v;
}

// async global->LDS 16B copy: LDS dest is wave-uniform base + lane*16 (HW),
// global src is per-lane.
static __device__ __forceinline__ void gload16(const bf16_t* g, bf16_t* l) {
  __builtin_amdgcn_global_load_lds(
      (const __attribute__((address_space(1))) u32*)g,
      (__attribute__((address_space(3))) u32*)l, 16, 0, 0);
}

// ---------------------------------------------------------------------------
// f32 -> bf16 bulk convert for TWO tensors in one launch (saves a dispatch
// gap). 8 elems/thread; blocks [0, n8a/256) cover a, the rest cover b.
// ---------------------------------------------------------------------------
__global__ __launch_bounds__(256) void cvt2_f32_bf16(
    const float* __restrict__ a, bf16_t* __restrict__ da, int n8a,
    const float* __restrict__ b, bf16_t* __restrict__ db, int n8b)
{
  const int i = blockIdx.x * 256 + threadIdx.x;
  const float* s; bf16_t* d; int idx;
  if (i < n8a) { s = a; d = da; idx = i; }
  else         { s = b; d = db; idx = i - n8a; if (idx >= n8b) return; }
  const float* p = s + (size_t)idx * 8;
  bf16x8 v;
#pragma unroll
  for (int u = 0; u < 8; ++u) v[u] = (bf16_t)p[u];
  *(bf16x8*)(d + (size_t)idx * 8) = v;
}

// ---------------------------------------------------------------------------
// GEMM (f32 path, layer1 only): C = act(A*B^T + bias), 128x128 tile, BK=32.
// ---------------------------------------------------------------------------
template <typename TA, typename TB>
__global__ __launch_bounds__(256) void gemm_bt(
    const TA* __restrict__ A, const TB* __restrict__ Bm,
    const float* __restrict__ bias, bf16_t* __restrict__ C,
    int M, int N, int K, int relu)
{
  __shared__ __align__(16) bf16_t As[128 * 32];
  __shared__ __align__(16) bf16_t Bs[128 * 32];

  const int tid  = threadIdx.x;
  const int lane = tid & 63;
  const int wave = tid >> 6;
  const int q    = lane >> 4;
  const int l15  = lane & 15;
  const int wr   = wave >> 1;
  const int wc   = wave & 1;
  const int m0   = blockIdx.y * 128;
  const int n0   = blockIdx.x * 128;

  f32x4 acc[4][4];
#pragma unroll
  for (int i = 0; i < 4; ++i)
#pragma unroll
    for (int j = 0; j < 4; ++j) zero4(acc[i][j]);

  const int se = wave * 512 + lane * 8;

  const int kt_count = K >> 5;
  for (int kt = 0; kt < kt_count; ++kt) {
    const int k0 = kt << 5;

    bf16x8 av[2], bv[2];
#pragma unroll
    for (int c = 0; c < 2; ++c) {
      const int e   = c * 2048 + se;
      const int row = e >> 5;
      const int col = e & 31;
      av[c] = load8_as_bf16<TA>(&A [(size_t)(m0 + row) * K + k0 + col]);
      bv[c] = load8_as_bf16<TB>(&Bm[(size_t)(n0 + row) * K + k0 + col]);
    }

    __syncthreads();
#pragma unroll
    for (int c = 0; c < 2; ++c) {
      *(bf16x8*)&As[c * 2048 + se] = av[c];
      *(bf16x8*)&Bs[c * 2048 + se] = bv[c];
    }
    __syncthreads();

    bf16x8 af[4], bfv[4];
#pragma unroll
    for (int i = 0; i < 4; ++i)
      af[i] = *(const bf16x8*)&As[(wr * 64 + i * 16 + l15) * 32 + q * 8];
#pragma unroll
    for (int j = 0; j < 4; ++j)
      bfv[j] = *(const bf16x8*)&Bs[(wc * 64 + j * 16 + l15) * 32 + q * 8];

#pragma unroll
    for (int i = 0; i < 4; ++i)
#pragma unroll
      for (int j = 0; j < 4; ++j)
        acc[i][j] = __builtin_amdgcn_mfma_f32_16x16x32_bf16(af[i], bfv[j], acc[i][j], 0, 0, 0);
  }

#pragma unroll
  for (int j = 0; j < 4; ++j) {
    const int n = n0 + wc * 64 + j * 16 + l15;
    const float bvl = bias[n];
#pragma unroll
    for (int i = 0; i < 4; ++i) {
      const int mbase = m0 + wr * 64 + i * 16 + q * 4;
#pragma unroll
      for (int r = 0; r < 4; ++r) {
        float v = acc[i][j][r] + bvl;
        if (relu) v = v > 0.0f ? v : 0.0f;
        C[(size_t)(mbase + r) * N + n] = (bf16_t)v;
      }
    }
  }
}

// ---------------------------------------------------------------------------
// GEMM (bf16 x bf16) with global_load_lds staging (m97 pattern). layer2 + xp.
// ---------------------------------------------------------------------------
__global__ __launch_bounds__(256) void gemm_lds(
    const bf16_t* __restrict__ A, const bf16_t* __restrict__ Bm,
    const float* __restrict__ bias, bf16_t* __restrict__ C,
    int M, int N, int K, int relu)
{
  __shared__ __align__(16) bf16_t As[128 * 32];
  __shared__ __align__(16) bf16_t Bs[128 * 32];

  const int tid  = threadIdx.x;
  const int lane = tid & 63;
  const int wave = tid >> 6;
  const int q    = lane >> 4;
  const int l15  = lane & 15;
  const int wr   = wave >> 1;
  const int wc   = wave & 1;
  const int m0   = blockIdx.y * 128;
  const int n0   = blockIdx.x * 128;

  f32x4 acc[4][4];
#pragma unroll
  for (int i = 0; i < 4; ++i)
#pragma unroll
    for (int j = 0; j < 4; ++j) zero4(acc[i][j]);

  const int sew = wave * 512;          // wave-uniform LDS chunk base (elems)
  const int se  = sew + lane * 8;

  const int kt_count = K >> 5;
  for (int kt = 0; kt < kt_count; ++kt) {
    const int k0 = kt << 5;

    __syncthreads();   // prior iteration's LDS reads complete
#pragma unroll
    for (int c = 0; c < 2; ++c) {
      const int e   = c * 2048 + se;
      const int row = e >> 5;
      const int col = e & 31;
      gload16(&A [(size_t)(m0 + row) * K + k0 + col], &As[c * 2048 + sew]);
      gload16(&Bm[(size_t)(n0 + row) * K + k0 + col], &Bs[c * 2048 + sew]);
    }
    asm volatile("s_waitcnt vmcnt(0)" ::: "memory");
    __syncthreads();   // staging visible to all waves

    bf16x8 af[4], bfv[4];
#pragma unroll
    for (int i = 0; i < 4; ++i)
      af[i] = *(const bf16x8*)&As[(wr * 64 + i * 16 + l15) * 32 + q * 8];
#pragma unroll
    for (int j = 0; j < 4; ++j)
      bfv[j] = *(const bf16x8*)&Bs[(wc * 64 + j * 16 + l15) * 32 + q * 8];

#pragma unroll
    for (int i = 0; i < 4; ++i)
#pragma unroll
      for (int j = 0; j < 4; ++j)
        acc[i][j] = __builtin_amdgcn_mfma_f32_16x16x32_bf16(af[i], bfv[j], acc[i][j], 0, 0, 0);
  }

#pragma unroll
  for (int j = 0; j < 4; ++j) {
    const int n = n0 + wc * 64 + j * 16 + l15;
    const float bvl = bias[n];
#pragma unroll
    for (int i = 0; i < 4; ++i) {
      const int mbase = m0 + wr * 64 + i * 16 + q * 4;
#pragma unroll
      for (int r = 0; r < 4; ++r) {
        float v = acc[i][j][r] + bvl;
        if (relu) v = v > 0.0f ? v : 0.0f;
        C[(size_t)(mbase + r) * N + n] = (bf16_t)v;
      }
    }
  }
}

// ---------------------------------------------------------------------------
// Persistent GRU scan, round 10 = round 7 (scan + fused layer3, the 1274us
// best) with ONE experimental variable changed:
//   BUSY-POLL instead of s_sleep in the flag spins. Hypothesis: with all
//   waves descheduled in s_sleep ~95% of the time, the clock governor
//   drops the core clock ~3x (r7: MfmaUtil*dur = 0.66us/step of MFMA-busy
//   vs 0.2us static) and wave re-wake adds latency. The agent-load
//   roundtrip (~0.3-0.7us) naturally paces the spin loop; no sleep needed.
// Plus T5: s_setprio(1) around the scan MFMA cluster (waves here have the
// role-split - pollers vs storer - where setprio measured +4-7%).
// Everything else is byte-identical to round 7.
// ---------------------------------------------------------------------------
#define WROW 2056   // 2048 + 8 bf16 pad
#define NCOPY 8

__global__ __launch_bounds__(512, 2) void gru_persistent(
    const float* __restrict__ W_hh, const float* __restrict__ b_hh,
    const bf16_t* __restrict__ xp, bf16_t* __restrict__ hs,
    unsigned* __restrict__ arr,
    const float* __restrict__ W3, const float* __restrict__ b3,
    bf16_t* __restrict__ out_s)
{
  __shared__ __align__(16) bf16_t Ws[24 * WROW];            // 98,688 B
  __shared__ __align__(16) bf16_t W3s[4 * WROW];            // 16,448 B
  __shared__ __align__(16) float hp_p[8][32][28];           // 28,672 B
  __shared__ __align__(16) float hp3[8][32][8];             //  8,192 B
  __shared__ __align__(16) unsigned short stage[32][8];     //    512 B

  const int tid  = threadIdx.x;
  const int lane = tid & 63;
  const int wave = tid >> 6;      // K-slice owner, 0..7
  const int q    = lane >> 4;
  const int l15  = lane & 15;
  const int bid  = blockIdx.x;
  const int j0   = bid * 8;       // h columns owned
  const int j0s  = bid * 4;       // out_s columns owned
  const int k0w  = wave * 256;

  // ---- Stage W_hh slice into LDS once (f32 -> bf16) ----
  for (int m = 0; m < 24; ++m) {
    const int gate = m >> 3;
    const float* src = W_hh + (size_t)(gate * 2048 + j0 + (m & 7)) * 2048;
    const int c = tid * 4;
    bf16x4 v;
#pragma unroll
    for (int u = 0; u < 4; ++u) v[u] = (bf16_t)src[c + u];
    *(bf16x4*)&Ws[m * WROW + c] = v;
  }
  // ---- Stage W3 slice into LDS once (f32 -> bf16) ----
  for (int m = 0; m < 4; ++m) {
    const float* src = W3 + (size_t)(j0s + m) * 2048;
    const int c = tid * 4;
    bf16x4 v;
#pragma unroll
    for (int u = 0; u < 4; ++u) v[u] = (bf16_t)src[c + u];
    *(bf16x4*)&W3s[m * WROW + c] = v;
  }

  // pointwise mapping: waves 0-3 (tid<256) -> (batch b, local col jj)
  const bool pw = tid < 256;
  const int b  = (tid >> 3) & 31;
  const int jj = tid & 7;
  const int jg = j0 + jj;
  float bh_r = 0.f, bh_z = 0.f, bh_n = 0.f;
  if (pw) {
    bh_r = b_hh[jg];
    bh_z = b_hh[2048 + jg];
    bh_n = b_hh[4096 + jg];
  }
  // out_s reduce mapping: waves 4-5 (tid in [256,384)) -> (batch, col)
  const bool sw = (tid >= 256) && (tid < 384);
  const int b3t = (tid - 256) >> 2;
  const int c3  = (tid - 256) & 3;
  float b3v = 0.f;
  if (sw) b3v = b3[j0s + c3];

  // matmul A-tiles: tile0 row = l15 (gates r,z), tile1 row = 16+(l15&7)
  const bf16_t* arow0 = &Ws[(size_t)l15 * WROW + k0w];
  const bf16_t* arow1 = &Ws[(size_t)(16 + (l15 & 7)) * WROW + k0w];
  // W3 A-tile: rows 0..3 used, lanes l15>=4 duplicate (results discarded)
  const bf16_t* arow3 = &W3s[(size_t)(l15 & 3) * WROW + k0w];

  float hcur = 0.0f;              // this thread's own h(b, jg)

  // xp for t=0
  float xr_c = 0.f, xz_c = 0.f, xn_c = 0.f;
  if (pw) {
    xr_c = (float)xp[(size_t)(b * 128 + 0) * 6144 + jg];
    xz_c = (float)xp[(size_t)(b * 128 + 0) * 6144 + 2048 + jg];
    xn_c = (float)xp[(size_t)(b * 128 + 0) * 6144 + 4096 + jg];
  }

  __syncthreads();   // Ws/W3s staged

  for (int t = 0; t < 128; ++t) {
    if (t > 0) {
      // ---- poll own producer slice of h[t-1] flags (copy bid&7) ----
      // BUSY-POLL: no s_sleep — keep the wave scheduled (clocks up,
      // no re-wake latency). Load roundtrip paces the loop.
      const int c = bid & 7;
      const u64* f64p =
          (const u64*)(arr + ((size_t)(t - 1) * NCOPY + c) * 256) + wave * 16;
      const u64 tgt = 0x0000000100000001ull;
      int guard = 0;
      for (;;) {
        u64 v = tgt;
        if (lane < 16)
          v = __hip_atomic_load(f64p + lane, __ATOMIC_RELAXED,
                                __HIP_MEMORY_SCOPE_AGENT);
        if (__all(v == tgt)) break;
        if (++guard > (1 << 20)) break;   // safety: never hang
      }

      // ---- hprev fragment burst: 16 independent 16B loads ----
      bf16x8 bfr[2][8];
#pragma unroll
      for (int ct = 0; ct < 2; ++ct) {
        const bf16_t* bp_ = hs + ((size_t)(ct * 16 + l15) * 128 + (t - 1)) * 2048
                               + k0w + q * 8;
#pragma unroll
        for (int win = 0; win < 8; ++win)
          bfr[ct][win] = *(const bf16x8*)(bp_ + win * 32);
      }

      f32x4 acc[2][2];
#pragma unroll
      for (int rt = 0; rt < 2; ++rt)
#pragma unroll
        for (int ct = 0; ct < 2; ++ct) zero4(acc[rt][ct]);

      __builtin_amdgcn_s_setprio(1);     // T5: favor MFMA-entering waves
#pragma unroll
      for (int win = 0; win < 8; ++win) {
        const bf16x8 a0 = *(const bf16x8*)(arow0 + win * 32 + q * 8);
        const bf16x8 a1 = *(const bf16x8*)(arow1 + win * 32 + q * 8);
        acc[0][0] = __builtin_amdgcn_mfma_f32_16x16x32_bf16(a0, bfr[0][win], acc[0][0], 0, 0, 0);
        acc[0][1] = __builtin_amdgcn_mfma_f32_16x16x32_bf16(a0, bfr[1][win], acc[0][1], 0, 0, 0);
        acc[1][0] = __builtin_amdgcn_mfma_f32_16x16x32_bf16(a1, bfr[0][win], acc[1][0], 0, 0, 0);
        acc[1][1] = __builtin_amdgcn_mfma_f32_16x16x32_bf16(a1, bfr[1][win], acc[1][1], 0, 0, 0);
      }

      // fused layer3: out_s partials for t-1, reusing bfr
      f32x4 acc3[2];
      zero4(acc3[0]); zero4(acc3[1]);
#pragma unroll
      for (int win = 0; win < 8; ++win) {
        const bf16x8 a3 = *(const bf16x8*)(arow3 + win * 32 + q * 8);
        acc3[0] = __builtin_amdgcn_mfma_f32_16x16x32_bf16(a3, bfr[0][win], acc3[0], 0, 0, 0);
        acc3[1] = __builtin_amdgcn_mfma_f32_16x16x32_bf16(a3, bfr[1][win], acc3[1], 0, 0, 0);
      }
      __builtin_amdgcn_s_setprio(0);

      // partials: D col = l15 (batch within ct-tile), row = q*4+reg
#pragma unroll
      for (int ct = 0; ct < 2; ++ct) {
        *(f32x4*)&hp_p[wave][ct * 16 + l15][q * 4] = acc[0][ct];
        if (q < 2)
          *(f32x4*)&hp_p[wave][ct * 16 + l15][16 + q * 4] = acc[1][ct];
      }
      if (q == 0) {   // W3 rows 0..3 live in q==0 lanes
        *(f32x4*)&hp3[wave][l15][0]      = acc3[0];
        *(f32x4*)&hp3[wave][16 + l15][0] = acc3[1];
      }
    }
    __syncthreads();   // (B) partials ready

    float xr_n = 0.f, xz_n = 0.f, xn_n = 0.f;
    if (pw) {
      float pr = 0.0f, pz = 0.0f, pn = 0.0f;
      if (t > 0) {
#pragma unroll
        for (int w = 0; w < 8; ++w) {
          pr += hp_p[w][b][jj];
          pz += hp_p[w][b][8 + jj];
          pn += hp_p[w][b][16 + jj];
        }
      }
      const float r_ = 1.0f / (1.0f + __expf(-(xr_c + pr + bh_r)));
      const float z_ = 1.0f / (1.0f + __expf(-(xz_c + pz + bh_z)));
      const float aa = xn_c + r_ * (pn + bh_n);
      const float et = __expf(-2.0f * aa);
      const float n_ = (1.0f - et) / (1.0f + et);
      hcur = (1.0f - z_) * n_ + z_ * hcur;

      if (t < 127) {
        const int tn = t + 1;
        xr_n = (float)xp[(size_t)(b * 128 + tn) * 6144 + jg];
        xz_n = (float)xp[(size_t)(b * 128 + tn) * 6144 + 2048 + jg];
        xn_n = (float)xp[(size_t)(b * 128 + tn) * 6144 + 4096 + jg];
      }

      union { bf16_t h; unsigned short u; } cv; cv.h = (bf16_t)hcur;
      stage[b][jj] = cv.u;
    } else if (sw && t > 0) {
      // fused layer3 reduce + relu + store out_s[:, t-1]
      float s3 = 0.0f;
#pragma unroll
      for (int w = 0; w < 8; ++w) s3 += hp3[w][b3t][c3];
      s3 += b3v;
      if (s3 < 0.0f) s3 = 0.0f;
      out_s[((size_t)b3t * 128 + (t - 1)) * 1024 + j0s + c3] = (bf16_t)s3;
    }
    __syncthreads();   // (A) stage ready; all LDS reads of step t done

    // ---- packed h store: wave 0 only, 32 x 16B coalesced sc0sc1 ----
    if (wave == 0 && lane < 32) {
      const i32x4 val = *(const i32x4*)&stage[lane][0];
      bf16_t* dst = hs + ((size_t)lane * 128 + t) * 2048 + j0;
      asm volatile("global_store_dwordx4 %0, %1, off sc0 sc1"
                   :: "v"(dst), "v"(val) : "memory");
    }
    if (wave == 0) {
      asm volatile("s_waitcnt vmcnt(0)" ::: "memory");  // stores at LLC
      if (lane < NCOPY)
        __hip_atomic_store(arr + ((size_t)t * NCOPY + lane) * 256 + bid, 1u,
                           __ATOMIC_RELAXED, __HIP_MEMORY_SCOPE_AGENT);
    }
    if (t < 127) {
      xr_c = xr_n; xz_c = xz_n; xn_c = xn_n;
    }
  }

  // ---- epilogue: out_s[:, 127] (needs h[127], flags published above) ----
  {
    const int c = bid & 7;
    const u64* f64p =
        (const u64*)(arr + ((size_t)127 * NCOPY + c) * 256) + wave * 16;
    const u64 tgt = 0x0000000100000001ull;
    int guard = 0;
    for (;;) {
      u64 v = tgt;
      if (lane < 16)
        v = __hip_atomic_load(f64p + lane, __ATOMIC_RELAXED,
                              __HIP_MEMORY_SCOPE_AGENT);
      if (__all(v == tgt)) break;
      if (++guard > (1 << 20)) break;
    }

    f32x4 acc3[2];
    zero4(acc3[0]); zero4(acc3[1]);
#pragma unroll
    for (int ct = 0; ct < 2; ++ct) {
      const bf16_t* bp_ = hs + ((size_t)(ct * 16 + l15) * 128 + 127) * 2048
                             + k0w + q * 8;
#pragma unroll
      for (int win = 0; win < 8; ++win) {
        const bf16x8 bv = *(const bf16x8*)(bp_ + win * 32);
        const bf16x8 a3 = *(const bf16x8*)(arow3 + win * 32 + q * 8);
        acc3[ct] = __builtin_amdgcn_mfma_f32_16x16x32_bf16(a3, bv, acc3[ct], 0, 0, 0);
      }
    }
    if (q == 0) {
      *(f32x4*)&hp3[wave][l15][0]      = acc3[0];
      *(f32x4*)&hp3[wave][16 + l15][0] = acc3[1];
    }
    __syncthreads();
    if (sw) {
      float s3 = 0.0f;
#pragma unroll
      for (int w = 0; w < 8; ++w) s3 += hp3[w][b3t][c3];
      s3 += b3v;
      if (s3 < 0.0f) s3 = 0.0f;
      out_s[((size_t)b3t * 128 + 127) * 1024 + j0s + c3] = (bf16_t)s3;
    }
  }
}

// ---------------------------------------------------------------------------
// Heads: per (b,t): 3 scalar heads + 4 sigmoid heads, 1024-dot each with a
// label-gathered f32 weight row. out_s is bf16, OUTPUT IS FLOAT32.
// ---------------------------------------------------------------------------
__global__ __launch_bounds__(256) void heads_kernel(
    const bf16_t* __restrict__ out_s, const int* __restrict__ labels,
    const float* __restrict__ W4, const float* __restrict__ b4,
    const float* __restrict__ W5, const float* __restrict__ b5,
    const float* __restrict__ W6, const float* __restrict__ b6,
    const float* __restrict__ Wp, const float* __restrict__ bp,
    float* __restrict__ out)
{
  const int bt  = blockIdx.x;
  const int b   = bt >> 7;         // T = 128
  const int lab = labels[b];
  const bf16_t* os  = out_s + (size_t)bt * 1024;
  const float* w4  = W4 + (size_t)lab * 1024;
  const float* w5  = W5 + (size_t)lab * 1024;
  const float* w6  = W6 + (size_t)lab * 1024;
  const float* wp0 = Wp + (size_t)lab * 1024;   // + p*65536 for plane p

  float s[7] = {0, 0, 0, 0, 0, 0, 0};
  for (int d = threadIdx.x; d < 1024; d += 256) {
    const float v = (float)os[d];
    s[0] += v * w4[d];
    s[1] += v * w5[d];
    s[2] += v * w6[d];
    s[3] += v * wp0[d];
    s[4] += v * wp0[65536 + d];
    s[5] += v * wp0[131072 + d];
    s[6] += v * wp0[196608 + d];
  }
#pragma unroll
  for (int i = 0; i < 7; ++i)
    for (int off = 32; off > 0; off >>= 1)
      s[i] += __shfl_down(s[i], off, 64);

  __shared__ float red[4][7];
  const int lane = threadIdx.x & 63, wave = threadIdx.x >> 6;
  if (lane == 0)
    for (int i = 0; i < 7; ++i) red[wave][i] = s[i];
  __syncthreads();
  if (threadIdx.x == 0) {
    float tsum[7];
    for (int i = 0; i < 7; ++i)
      tsum[i] = red[0][i] + red[1][i] + red[2][i] + red[3][i];
    out[bt]        = tsum[0] + b4[lab];
    out[4096 + bt] = tsum[1] + b5[lab];
    out[8192 + bt] = tsum[2] + b6[lab];
#pragma unroll
    for (int p = 0; p < 4; ++p) {
      const float v = tsum[3 + p] + bp[p * 64 + lab];
      out[12288 + p * 4096 + bt] = 1.0f / (1.0f + __expf(-v));
    }
  }
}

// ---------------------------------------------------------------------------
extern "C" void kernel_launch(void* const* d_in, const int* in_sizes, int n_in,
                              void* d_out, int out_size, void* d_ws, size_t ws_size,
                              hipStream_t stream)
{
  const float* x     = (const float*)d_in[0];
  const int*   label = (const int*)d_in[1];
  const float* W1    = (const float*)d_in[2];
  const float* b1    = (const float*)d_in[3];
  const float* W2    = (const float*)d_in[4];
  const float* b2    = (const float*)d_in[5];
  const float* W_ih  = (const float*)d_in[6];
  const float* b_ih  = (const float*)d_in[7];
  const float* W_hh  = (const float*)d_in[8];
  const float* b_hh  = (const float*)d_in[9];
  const float* W3    = (const float*)d_in[10];
  const float* b3    = (const float*)d_in[11];
  const float* W4    = (const float*)d_in[12];
  const float* b4    = (const float*)d_in[13];
  const float* W5    = (const float*)d_in[14];
  const float* b5    = (const float*)d_in[15];
  const float* W6    = (const float*)d_in[16];
  const float* b6    = (const float*)d_in[17];
  const float* Wp    = (const float*)d_in[18];
  const float* bp    = (const float*)d_in[19];

  // Workspace map (96 MB), bf16 internals (identical to round 7 — verified):
  //   W_ihb [0,24)   bf16 W_ih   (cvt .. xp GEMM)
  //   hs    [0,16)   (B,T,2048)  (GRU ..)           [reuses W_ihb region]
  //   out_s [16,24)  4096x1024   (GRU .. heads)     [reuses W_ihb region]
  //   out2  [24,40)  4096x2048   (layer2 .. xp GEMM)
  //   W2b   [40,44)  bf16 W2     (cvt .. layer2)
  //   out1  [44,52)  4096x1024   (layer1 .. layer2)
  //   xp    [47,95)  4096x6144   (xp GEMM .. GRU)   [reuses out1 region]
  //   arr   [95,96)  flags (memset 0; touched by nothing else)
  char* ws = (char*)d_ws;
  bf16_t* W_ihb = (bf16_t*)(ws);
  bf16_t* out2  = (bf16_t*)(ws + (24u << 20));
  bf16_t* W2b   = (bf16_t*)(ws + (40u << 20));
  bf16_t* out1  = (bf16_t*)(ws + (44u << 20));
  bf16_t* xp    = (bf16_t*)(ws + (47u << 20));
  bf16_t* hs    = (bf16_t*)(ws);
  bf16_t* out_s = (bf16_t*)(ws + (16u << 20));
  unsigned* arr = (unsigned*)(ws + (95u << 20));
  float*  outp  = (float*)d_out;

  hipMemsetAsync(d_out, 0, (size_t)out_size * sizeof(float), stream);
  hipMemsetAsync(arr, 0, 1u << 20, stream);   // arrival flags

  dim3 blk(256);
  // pre-convert f32 weights -> bf16 (both in ONE launch)
  cvt2_f32_bf16<<<dim3(7168), blk, 0, stream>>>(W_ih, W_ihb, 1572864,
                                                W2, W2b, 262144);
  // layer1: (4096x32)*(1024x32)^T, relu (f32 path, tiny K)
  gemm_bt<float, float><<<dim3(8, 32), blk, 0, stream>>>(x, W1, b1, out1, 4096, 1024, 32, 1);
  // layer2: (4096x1024)*(2048x1024)^T, relu — gload_lds path
  gemm_lds<<<dim3(16, 32), blk, 0, stream>>>(out1, W2b, b2, out2, 4096, 2048, 1024, 1);
  // xp: (4096x2048)*(6144x2048)^T + b_ih — gload_lds path
  gemm_lds<<<dim3(48, 32), blk, 0, stream>>>(out2, W_ihb, b_ih, xp, 4096, 6144, 2048, 0);
  // GRU scan + fused layer3: persistent cooperative kernel (busy-poll)
  {
    void* gru_args[] = { (void*)&W_hh, (void*)&b_hh, (void*)&xp, (void*)&hs,
                         (void*)&arr, (void*)&W3, (void*)&b3, (void*)&out_s };
    hipLaunchCooperativeKernel((void*)gru_persistent, dim3(256), dim3(512),
                               gru_args, 0, stream);
  }
  // heads (f32 weights, f32 out)
  heads_kernel<<<dim3(4096), blk, 0, stream>>>(out_s, label, W4, b4, W5, b5, W6, b6, Wp, bp, outp);
}